// Round 12
// baseline (324.143 us; speedup 1.0000x reference)
//
#include <hip/hip_runtime.h>
#include <hip/hip_bf16.h>
#include <stdint.h>

#define NN 50000
#define NE 400000
#define DD 256
#define MPAD 50048   /* 782*64 */
#define EPSV 1e-5f
#define NSB 49       /* scan blocks: 49*1024 >= NN */
#define NWID 1564    /* stats writer rows: 782 m-blocks * 2 wm */
#define NEB 1563     /* edge blocks: ceil(NE/256) */

typedef __attribute__((ext_vector_type(8))) short bf16x8;
typedef __attribute__((ext_vector_type(8))) unsigned short u16x8;
typedef __attribute__((ext_vector_type(4))) float f32x4;

static __device__ __forceinline__ float bf2f(unsigned short u){
  union{unsigned int i; float f;} x; x.i=((unsigned int)u)<<16; return x.f;
}
static __device__ __forceinline__ unsigned short f2bf(float f){
  union{float f; unsigned int i;} x; x.f=f;
  return (unsigned short)((x.i + 0x7FFFu + ((x.i>>16)&1u))>>16);
}
static __device__ __forceinline__ void gl_lds16(const void* g, void* l){
  __builtin_amdgcn_global_load_lds((const __attribute__((address_space(1))) void*)g,
                                   (__attribute__((address_space(3))) void*)l, 16, 0, 0);
}

/* ---------------- graph preprocessing ---------------- */

/* blocks [0,NEB): edge degree count; blocks [NEB,NEB+768): W->Wt bf16 transpose */
__global__ void k_degreeW(const int* __restrict__ ei, int* __restrict__ degi_out,
                          int* __restrict__ degi_in,
                          const float* __restrict__ W0, const float* __restrict__ W1,
                          const float* __restrict__ W2, unsigned short* __restrict__ Wt){
  if(blockIdx.x < NEB){
    int e = blockIdx.x*256 + threadIdx.x;
    if(e < NE){
      atomicAdd(&degi_out[ei[e]], 1);
      atomicAdd(&degi_in[ei[NE + e]], 1);
    }
  } else {
    int t = (blockIdx.x - NEB)*256 + threadIdx.x;   /* 3*65536 */
    int l = t >> 16, r = t & 65535;
    int k = r >> 8, n = r & 255;
    const float* W = (l==0) ? W0 : (l==1) ? W1 : W2;
    Wt[(size_t)l*65536 + n*256 + k] = f2bf(W[k*256 + n]);
  }
}

/* per-block sums of degi_in + dso/dsi/rds + per-block 64-bin degree histogram
   (LDS atomics only; one coalesced global write) */
__global__ void k_bsum(const int* __restrict__ degi_in, const int* __restrict__ degi_out,
                       int* __restrict__ bsum, float* __restrict__ dso,
                       float* __restrict__ dsi, float* __restrict__ rds,
                       int* __restrict__ ghist){
  __shared__ int wsum[16];
  __shared__ int lhist[64];
  int tid = threadIdx.x, lane = tid & 63, wv = tid >> 6;
  if(tid < 64) lhist[tid] = 0;
  __syncthreads();
  int i = blockIdx.x*1024 + tid;
  int v = (i < NN) ? degi_in[i] : 0;
  if(i < NN){
    float go = (float)max(degi_out[i],1);
    dso[i] = rsqrtf(go);
    rds[i] = sqrtf(go);          /* 1/dso */
    dsi[i] = rsqrtf((float)max(v,1));
    atomicAdd(&lhist[min(v,63)], 1);   /* LDS atomic - cheap */
  }
  int r = v;
  for(int off=1; off<64; off<<=1) r += __shfl_xor(r, off);
  if(lane==0) wsum[wv] = r;
  __syncthreads();
  if(tid < 16){
    int t = wsum[tid];
    for(int off=1; off<16; off<<=1) t += __shfl_xor(t, off);
    if(tid==0) bsum[blockIdx.x] = t;
  }
  if(tid < 64) ghist[blockIdx.x*64 + tid] = lhist[tid];
}

/* intra-block exclusive scan (block offset = wave-reduce of bsum) -> rowptr,
   cursor; degree-bucket scatter -> perm. Per-(block,bin) offsets computed
   in-kernel from ghist (12.5KB redundant read per block; no extra launch). */
__global__ void k_scatter(const int* __restrict__ cnt, const int* __restrict__ bsum,
                          int* __restrict__ rowptr, int* __restrict__ cursor,
                          const int* __restrict__ ghist, int* __restrict__ perm){
  __shared__ int wsum[16];
  __shared__ int s_boff;
  __shared__ int lcur[64];
  int tid = threadIdx.x, lane = tid & 63, wv = tid >> 6;
  if(tid < 64){
    int b = (tid < NSB && tid < (int)blockIdx.x) ? bsum[tid] : 0;
    for(int off=1; off<64; off<<=1) b += __shfl_xor(b, off);
    if(tid==0) s_boff = b;
  } else if(tid >= 64 && tid < 128){
    int v = tid - 64;
    int tot = 0, pre = 0;
    for(int b=0; b<NSB; ++b){
      int h = ghist[b*64 + v];
      tot += h;
      if(b < (int)blockIdx.x) pre += h;
    }
    int sc = tot;
    for(int off=1; off<64; off<<=1){
      int t = __shfl_up(sc, off);
      if(v >= off) sc += t;
    }
    lcur[v] = (sc - tot) + pre;   /* exclusive bin offset + prior blocks */
  }
  int i = blockIdx.x*1024 + tid;
  int v = (i < NN) ? cnt[i] : 0;
  int sc = v;
  for(int off=1; off<64; off<<=1){
    int t = __shfl_up(sc, off);
    if(lane >= off) sc += t;
  }
  if(lane==63) wsum[wv] = sc;
  __syncthreads();
  if(wv==0){
    int t = (lane<16) ? wsum[lane] : 0;
    for(int off=1; off<16; off<<=1){
      int u = __shfl_up(t, off);
      if(lane >= off) t += u;
    }
    if(lane<16) wsum[lane] = t;
  }
  __syncthreads();
  int woff = (wv==0) ? 0 : wsum[wv-1];
  int ex = s_boff + woff + sc - v;
  if(i < NN){
    rowptr[i] = ex; cursor[i] = ex;
    int p = atomicAdd(&lcur[min(v,63)], 1);   /* LDS atomic - cheap */
    perm[p] = i;
  }
  if(blockIdx.x==0 && tid==0) rowptr[NN] = NE;
}

/* blocks [0,NEB): CSR fill; blocks [NEB,...): hs = x*dso bf16 */
__global__ void k_fillhs(const int* __restrict__ ei, int* __restrict__ cursor,
                         int* __restrict__ eidx,
                         const float* __restrict__ x, const float* __restrict__ dso,
                         unsigned short* __restrict__ hs){
  if(blockIdx.x < NEB){
    int e = blockIdx.x*256 + threadIdx.x;
    if(e < NE){
      int c = ei[NE + e];
      int p = atomicAdd(&cursor[c], 1);
      eidx[p] = ei[e];
    }
  } else {
    int t = (blockIdx.x - NEB)*256 + threadIdx.x;   /* NN*64 */
    int row = t >> 6, c4 = (t & 63) << 2;
    if(row < NN){
      float s = dso[row];
      float4 v = *(const float4*)(x + (size_t)row*256 + c4);
      ushort4 o;
      o.x = f2bf(v.x*s); o.y = f2bf(v.y*s); o.z = f2bf(v.z*s); o.w = f2bf(v.w*s);
      *(ushort4*)(hs + (size_t)row*256 + c4) = o;
    }
  }
}

/* TWO nodes per half-wave (adjacent in degree-sorted perm -> equal degree).
   16 independent 16B gathers in flight; index-load latency amortized 2x.
   NORM=1: y_contrib = relu(fma(v,cs,ch)) * dso[src], computed as
   fma(max(fma(v,cs,ch),0), dso, acc) - 4 VALU/elem. */
template<int NORM>
__global__ void k_agg(const unsigned short* __restrict__ src, const int* __restrict__ rowptr,
                      const int* __restrict__ eidx, const int* __restrict__ perm,
                      const float* __restrict__ cs, const float* __restrict__ ch,
                      const float* __restrict__ dso,
                      unsigned short* __restrict__ agg){
  const int hw = threadIdx.x >> 5, l32 = threadIdx.x & 31;
  const int g0 = blockIdx.x*16 + hw*2;
  const int nA = (g0   < NN) ? perm[g0]   : g0;
  const int nB = (g0+1 < NN) ? perm[g0+1] : g0+1;
  float csr[8], chr[8];
  if(NORM){
    #pragma unroll
    for(int k2=0;k2<8;k2++){ csr[k2] = cs[l32*8+k2]; chr[k2] = ch[l32*8+k2]; }
  }
  float aA[8] = {0.f,0.f,0.f,0.f,0.f,0.f,0.f,0.f};
  float aB[8] = {0.f,0.f,0.f,0.f,0.f,0.f,0.f,0.f};
  int sA=0,eA=0,sB=0,eB=0;
  if(nA < NN){ sA = rowptr[nA]; eA = rowptr[nA+1]; }
  if(nB < NN){ sB = rowptr[nB]; eB = rowptr[nB+1]; }
  const int dA = eA - sA, dB = eB - sB;
  const int dmax = max(dA, dB);
  for(int base=0; base<dmax; base+=32){
    int iA = (base + l32 < dA) ? eidx[sA + base + l32] : 0;
    int iB = (base + l32 < dB) ? eidx[sB + base + l32] : 0;
    int cm = min(dmax - base, 32);
    for(int g=0; g<cm; g+=8){
      int siA[8], siB[8];
      #pragma unroll
      for(int i=0;i<8;i++){ siA[i] = __shfl(iA, g+i, 32); siB[i] = __shfl(iB, g+i, 32); }
      u16x8 vA[8], vB[8];
      #pragma unroll
      for(int i=0;i<8;i++) vA[i] = *(const u16x8*)(src + (size_t)siA[i]*256 + l32*8);
      #pragma unroll
      for(int i=0;i<8;i++) vB[i] = *(const u16x8*)(src + (size_t)siB[i]*256 + l32*8);
      float dvA[8], dvB[8];
      if(NORM){
        #pragma unroll
        for(int i=0;i<8;i++){ dvA[i] = dso[siA[i]]; dvB[i] = dso[siB[i]]; }
      }
      #pragma unroll
      for(int i=0;i<8;i++){
        if(base+g+i < dA){
          #pragma unroll
          for(int k2=0;k2<8;k2++){
            float y = bf2f(vA[i][k2]);
            if(NORM) aA[k2] = fmaf(fmaxf(fmaf(y, csr[k2], chr[k2]), 0.f), dvA[i], aA[k2]);
            else     aA[k2] += y;
          }
        }
        if(base+g+i < dB){
          #pragma unroll
          for(int k2=0;k2<8;k2++){
            float y = bf2f(vB[i][k2]);
            if(NORM) aB[k2] = fmaf(fmaxf(fmaf(y, csr[k2], chr[k2]), 0.f), dvB[i], aB[k2]);
            else     aB[k2] += y;
          }
        }
      }
    }
  }
  if(g0 < MPAD){
    u16x8 o;
    #pragma unroll
    for(int k2=0;k2<8;k2++) o[k2] = f2bf(aA[k2]);
    *(u16x8*)(agg + (size_t)nA*256 + l32*8) = o;
  }
  if(g0+1 < MPAD){
    u16x8 o;
    #pragma unroll
    for(int k2=0;k2<8;k2++) o[k2] = f2bf(aB[k2]);
    *(u16x8*)(agg + (size_t)nB*256 + l32*8) = o;
  }
}

/* GEMM 64x128 tile, BK=64, double-buffered 48KB LDS, 2-phase:
   STAGE(next) issued BEFORE compute(cur); one __syncthreads per K-step.
   grid (2, 782). Epilogue operands hoisted before the K-loop.
   out[m][n] = (sum_k A[m][k]*W[k][n] + b[n]) * dsi[m] (+ residual).
   RESMODE: 0=none, 2=bf16 resb * per-row rds (layer0: hs/dso = x),
   3=bf16 resb + fused norm+relu (rcs/rch).
   STATS: per-(m-block,wm) column partials, transposed [col][NWID]. */
template<int RESMODE, int STATS, int OUTBF>
__global__ __launch_bounds__(256) void k_gemm(
    const unsigned short* __restrict__ A,    /* [MPAD][256] bf16 */
    const unsigned short* __restrict__ Bt,   /* [256][256] bf16 = W^T */
    const float* __restrict__ bias,
    const float* __restrict__ dsi,
    const unsigned short* __restrict__ resb,
    const float* __restrict__ rds,
    const float* __restrict__ rcs, const float* __restrict__ rch,
    void* __restrict__ outp,
    float* __restrict__ ps, float* __restrict__ pq)
{
  __shared__ __align__(16) unsigned char smem[49152];   /* 2 x (A 8KB + B 16KB) */
  const int tid = threadIdx.x;
  const int w = tid >> 6, lane = tid & 63;
  const int m0 = blockIdx.y * 64, n0 = blockIdx.x * 128;
  const int wm = w & 1, wn = w >> 1;

  /* ---- hoisted epilogue operands (fly under the K-loop) ---- */
  const int colb = n0 + wn*64 + (lane & 15);
  float bs[4], rcsv[4], rchv[4];
  #pragma unroll
  for(int nf=0; nf<4; ++nf) bs[nf] = bias[colb + nf*16];
  if(RESMODE==3){
    #pragma unroll
    for(int nf=0; nf<4; ++nf){ rcsv[nf] = rcs[colb + nf*16]; rchv[nf] = rch[colb + nf*16]; }
  }
  float dv[8], rdv[8];
  unsigned short rvb[32];
  #pragma unroll
  for(int mf=0; mf<2; ++mf){
    const int growb = m0 + wm*32 + mf*16 + ((lane>>4)<<2);
    #pragma unroll
    for(int j=0; j<4; ++j){
      const int grow = growb + j;
      const bool ok = grow < NN;
      dv[mf*4+j] = ok ? dsi[grow] : 0.f;
      if(RESMODE==2) rdv[mf*4+j] = ok ? rds[grow] : 0.f;
      if(RESMODE){
        const size_t rb = (size_t)grow * 256;
        #pragma unroll
        for(int nf=0; nf<4; ++nf)
          rvb[mf*16+j*4+nf] = ok ? resb[rb + colb + nf*16] : (unsigned short)0;
      }
    }
  }

  f32x4 acc[2][4];
  #pragma unroll
  for(int i=0;i<2;i++)
    #pragma unroll
    for(int j=0;j<4;j++) acc[i][j] = (f32x4){0.f,0.f,0.f,0.f};

  const char* Ab = (const char*)A;
  const char* Bb = (const char*)Bt;

  auto STAGE = [&](int buf, int kt){
    unsigned char* sA = smem + buf*24576;
    unsigned char* sB = sA + 8192;
    #pragma unroll
    for(int it=0; it<2; ++it){
      const int flat = it*256 + tid;
      const int row = flat >> 3, ch_ = flat & 7;
      const int sw = ch_ ^ (row & 7);
      gl_lds16(Ab + (size_t)(m0+row)*512 + kt*128 + sw*16,
               sA + (size_t)flat*16);
    }
    #pragma unroll
    for(int it=0; it<4; ++it){
      const int flat = it*256 + tid;
      const int row = flat >> 3, ch_ = flat & 7;
      const int sw = ch_ ^ (row & 7);
      gl_lds16(Bb + (size_t)(n0+row)*512 + kt*128 + sw*16,
               sB + (size_t)flat*16);
    }
  };

  STAGE(0, 0);
  __syncthreads();

  for(int kt=0; kt<4; ++kt){
    const int cur = kt & 1;
    if(kt < 3) STAGE(cur^1, kt+1);        /* loads fly during MFMA below */
    unsigned char* sA = smem + cur*24576;
    unsigned char* sB = sA + 8192;
    #pragma unroll
    for(int ks=0; ks<2; ++ks){
      const int ca = ks*4 + (lane >> 4);
      bf16x8 av[2], bv[4];
      #pragma unroll
      for(int f=0; f<2; ++f){
        const int ra = wm*32 + f*16 + (lane & 15);
        av[f] = *(const bf16x8*)(sA + ra*128 + ((ca ^ (ra & 7)) << 4));
      }
      #pragma unroll
      for(int f=0; f<4; ++f){
        const int rb = wn*64 + f*16 + (lane & 15);
        bv[f] = *(const bf16x8*)(sB + rb*128 + ((ca ^ (rb & 7)) << 4));
      }
      #pragma unroll
      for(int mf=0; mf<2; ++mf)
        #pragma unroll
        for(int nf=0; nf<4; ++nf)
          acc[mf][nf] = __builtin_amdgcn_mfma_f32_16x16x32_bf16(av[mf], bv[nf], acc[mf][nf], 0,0,0);
    }
    __syncthreads();   /* drains next-tile loads (overlapped with MFMA) */
  }

  /* ---- epilogue: C row = (lane>>4)*4+j, col = lane&15 (per 16x16 frag) ---- */
  float s[4] = {0.f,0.f,0.f,0.f}, q[4] = {0.f,0.f,0.f,0.f};
  #pragma unroll
  for(int mf=0; mf<2; ++mf){
    const int growb = m0 + wm*32 + mf*16 + ((lane>>4)<<2);
    #pragma unroll
    for(int j=0; j<4; ++j){
      const int grow = growb + j;
      if(grow < NN){
        const size_t rb = (size_t)grow * 256;
        #pragma unroll
        for(int nf=0; nf<4; ++nf){
          float v = (acc[mf][nf][j] + bs[nf]) * dv[mf*4+j];
          if(RESMODE==2) v += bf2f(rvb[mf*16+j*4+nf]) * rdv[mf*4+j];
          if(RESMODE==3) v += fmaxf(fmaf(bf2f(rvb[mf*16+j*4+nf]), rcsv[nf], rchv[nf]), 0.f);
          if(OUTBF) ((unsigned short*)outp)[rb + colb + nf*16] = f2bf(v);
          else      ((float*)outp)[rb + colb + nf*16] = v;
          if(STATS){ s[nf] += v; q[nf] += v*v; }
        }
      }
    }
  }
  if(STATS){
    const int wid = blockIdx.y*2 + wm;
    #pragma unroll
    for(int nf=0; nf<4; ++nf){
      float sv = s[nf], qv = q[nf];
      sv += __shfl_xor(sv, 16); sv += __shfl_xor(sv, 32);
      qv += __shfl_xor(qv, 16); qv += __shfl_xor(qv, 32);
      if(lane < 16){
        ps[(size_t)(colb + nf*16)*NWID + wid] = sv;
        pq[(size_t)(colb + nf*16)*NWID + wid] = qv;
      }
    }
  }
}

/* one block per column: reduce NWID partials (coalesced), finalize cs/ch */
__global__ void k_statsall(const float* __restrict__ ps, const float* __restrict__ pq,
                           const float* __restrict__ g, const float* __restrict__ be,
                           float* __restrict__ cs, float* __restrict__ ch){
  __shared__ float rs[4], rq[4];
  int c = blockIdx.x, t = threadIdx.x;
  float s = 0.f, q = 0.f;
  for(int r = t; r < NWID; r += 256){
    s += ps[(size_t)c*NWID + r];
    q += pq[(size_t)c*NWID + r];
  }
  for(int off=1; off<64; off<<=1){ s += __shfl_xor(s, off); q += __shfl_xor(q, off); }
  if((t & 63) == 0){ rs[t>>6] = s; rq[t>>6] = q; }
  __syncthreads();
  if(t == 0){
    float S = rs[0]+rs[1]+rs[2]+rs[3], Q = rq[0]+rq[1]+rq[2]+rq[3];
    float mu  = S * (1.0f/NN);
    float var = fmaxf(Q * (1.0f/NN) - mu*mu, 0.f);
    float inv = rsqrtf(var + EPSV);
    float sc = g[c] * inv;
    cs[c] = sc;
    ch[c] = be[c] - mu * sc;
  }
}

extern "C" void kernel_launch(void* const* d_in, const int* in_sizes, int n_in,
                              void* d_out, int out_size, void* d_ws, size_t ws_size,
                              hipStream_t stream){
  (void)in_sizes; (void)n_in; (void)out_size;
  const float* x  = (const float*)d_in[0];
  const int*   ei = (const int*)d_in[1];
  const float* Wl[3]  = {(const float*)d_in[2], (const float*)d_in[6], (const float*)d_in[10]};
  const float* bl[3]  = {(const float*)d_in[3], (const float*)d_in[7], (const float*)d_in[11]};
  const float* gl[2]  = {(const float*)d_in[4], (const float*)d_in[8]};
  const float* bel[2] = {(const float*)d_in[5], (const float*)d_in[9]};

  char* base = (char*)d_ws;
  size_t off = 0;
  auto alloc = [&](size_t bytes)->char* {
    char* r = base + off;
    off = (off + bytes + 511) & ~(size_t)511;
    return r;
  };
  int* degi_out = (int*)alloc((size_t)2*NN*4);
  int* degi_in  = degi_out + NN;
  int* ghist    = (int*)alloc((size_t)NSB*64*4);
  float* dso    = (float*)alloc((size_t)NN*4);
  float* dsi    = (float*)alloc((size_t)NN*4);
  float* rds    = (float*)alloc((size_t)NN*4);
  int* rowptr   = (int*)alloc((size_t)(NN+1)*4);
  int* cursor   = (int*)alloc((size_t)NN*4);
  int* eidx     = (int*)alloc((size_t)NE*4);
  int* bsum     = (int*)alloc((size_t)NSB*4);
  int* perm     = (int*)alloc((size_t)NN*4);
  unsigned short* Wt = (unsigned short*)alloc((size_t)3*65536*2);
  float* ps     = (float*)alloc((size_t)NWID*256*4);
  float* pq     = (float*)alloc((size_t)NWID*256*4);
  float* cs0    = (float*)alloc(1024);
  float* ch0    = (float*)alloc(1024);
  float* cs1    = (float*)alloc(1024);
  float* ch1    = (float*)alloc(1024);
  unsigned short* hs  = (unsigned short*)alloc((size_t)NN*256*2);
  unsigned short* agg = (unsigned short*)alloc((size_t)MPAD*256*2);
  unsigned short* ob0 = (unsigned short*)alloc((size_t)MPAD*256*2);
  unsigned short* ob1 = (unsigned short*)alloc((size_t)MPAD*256*2);
  if(off > ws_size) return;   /* workspace too small: fail visibly */

  /* graph prep (layer-invariant) */
  (void)hipMemsetAsync(degi_out, 0, (size_t)2*NN*4, stream);
  k_degreeW<<<NEB + 768, 256, 0, stream>>>(ei, degi_out, degi_in, Wl[0], Wl[1], Wl[2], Wt);
  k_bsum<<<NSB, 1024, 0, stream>>>(degi_in, degi_out, bsum, dso, dsi, rds, ghist);
  k_scatter<<<NSB, 1024, 0, stream>>>(degi_in, bsum, rowptr, cursor, ghist, perm);
  k_fillhs<<<NEB + (NN*64+255)/256, 256, 0, stream>>>(ei, cursor, eidx, x, dso, hs);

  dim3 gg(2, 782);
  /* layer 0: gather hs; residual = hs * rds (= x), stats -> ob0 */
  k_agg<0><<<MPAD/16, 256, 0, stream>>>(hs, rowptr, eidx, perm, nullptr, nullptr, nullptr, agg);
  k_gemm<2,1,1><<<gg, 256, 0, stream>>>(agg, Wt, bl[0], dsi, hs, rds, nullptr, nullptr,
                                        ob0, ps, pq);
  k_statsall<<<256, 256, 0, stream>>>(ps, pq, gl[0], bel[0], cs0, ch0);
  /* layer 1: gather = norm0(ob0) on the fly; residual = norm0(ob0) in epilogue */
  k_agg<1><<<MPAD/16, 256, 0, stream>>>(ob0, rowptr, eidx, perm, cs0, ch0, dso, agg);
  k_gemm<3,1,1><<<gg, 256, 0, stream>>>(agg, Wt + 65536, bl[1], dsi, ob0, nullptr, cs0, ch0,
                                        ob1, ps, pq);
  k_statsall<<<256, 256, 0, stream>>>(ps, pq, gl[1], bel[1], cs1, ch1);
  /* layer 2: gather = norm1(ob1) on the fly; no residual, f32 out */
  k_agg<1><<<MPAD/16, 256, 0, stream>>>(ob1, rowptr, eidx, perm, cs1, ch1, dso, agg);
  k_gemm<0,0,0><<<gg, 256, 0, stream>>>(agg, Wt + 2*65536, bl[2], dsi, nullptr, nullptr,
                                        nullptr, nullptr, d_out, nullptr, nullptr);
}

// Round 13
// 273.212 us; speedup vs baseline: 1.1864x; 1.1864x over previous
//
#include <hip/hip_runtime.h>
#include <hip/hip_bf16.h>
#include <stdint.h>

#define NN 50000
#define NE 400000
#define DD 256
#define MPAD 50048   /* 782*64 */
#define EPSV 1e-5f
#define NSB 49       /* scan blocks: 49*1024 >= NN */
#define NWID 1564    /* stats writer rows: 782 m-blocks * 2 wm */
#define NEB 1563     /* edge blocks: ceil(NE/256) */

typedef __attribute__((ext_vector_type(8))) short bf16x8;
typedef __attribute__((ext_vector_type(8))) unsigned short u16x8;
typedef __attribute__((ext_vector_type(4))) float f32x4;

static __device__ __forceinline__ float bf2f(unsigned short u){
  union{unsigned int i; float f;} x; x.i=((unsigned int)u)<<16; return x.f;
}
static __device__ __forceinline__ unsigned short f2bf(float f){
  union{float f; unsigned int i;} x; x.f=f;
  return (unsigned short)((x.i + 0x7FFFu + ((x.i>>16)&1u))>>16);
}
static __device__ __forceinline__ void gl_lds16(const void* g, void* l){
  __builtin_amdgcn_global_load_lds((const __attribute__((address_space(1))) void*)g,
                                   (__attribute__((address_space(3))) void*)l, 16, 0, 0);
}

/* ---------------- graph preprocessing ---------------- */

/* blocks [0,NEB): edge degree count; blocks [NEB,NEB+768): W->Wt bf16 transpose */
__global__ void k_degreeW(const int* __restrict__ ei, int* __restrict__ degi_out,
                          int* __restrict__ degi_in,
                          const float* __restrict__ W0, const float* __restrict__ W1,
                          const float* __restrict__ W2, unsigned short* __restrict__ Wt){
  if(blockIdx.x < NEB){
    int e = blockIdx.x*256 + threadIdx.x;
    if(e < NE){
      atomicAdd(&degi_out[ei[e]], 1);
      atomicAdd(&degi_in[ei[NE + e]], 1);
    }
  } else {
    int t = (blockIdx.x - NEB)*256 + threadIdx.x;   /* 3*65536 */
    int l = t >> 16, r = t & 65535;
    int k = r >> 8, n = r & 255;
    const float* W = (l==0) ? W0 : (l==1) ? W1 : W2;
    Wt[(size_t)l*65536 + n*256 + k] = f2bf(W[k*256 + n]);
  }
}

/* per-block sums of degi_in + dso/dsi/rds */
__global__ void k_bsum(const int* __restrict__ degi_in, const int* __restrict__ degi_out,
                       int* __restrict__ bsum, float* __restrict__ dso,
                       float* __restrict__ dsi, float* __restrict__ rds){
  __shared__ int wsum[16];
  int tid = threadIdx.x, lane = tid & 63, wv = tid >> 6;
  int i = blockIdx.x*1024 + tid;
  int v = (i < NN) ? degi_in[i] : 0;
  if(i < NN){
    float go = (float)max(degi_out[i],1);
    dso[i] = rsqrtf(go);
    rds[i] = sqrtf(go);          /* 1/dso */
    dsi[i] = rsqrtf((float)max(v,1));
  }
  int r = v;
  for(int off=1; off<64; off<<=1) r += __shfl_xor(r, off);
  if(lane==0) wsum[wv] = r;
  __syncthreads();
  if(tid < 16){
    int t = wsum[tid];
    for(int off=1; off<16; off<<=1) t += __shfl_xor(t, off);
    if(tid==0) bsum[blockIdx.x] = t;
  }
}

/* intra-block exclusive scan (block offset = wave-reduce of bsum) -> rowptr, cursor */
__global__ void k_scatter(const int* __restrict__ cnt, const int* __restrict__ bsum,
                          int* __restrict__ rowptr, int* __restrict__ cursor){
  __shared__ int wsum[16];
  __shared__ int s_boff;
  int tid = threadIdx.x, lane = tid & 63, wv = tid >> 6;
  if(tid < 64){
    int b = (tid < NSB && tid < (int)blockIdx.x) ? bsum[tid] : 0;
    for(int off=1; off<64; off<<=1) b += __shfl_xor(b, off);
    if(tid==0) s_boff = b;
  }
  int i = blockIdx.x*1024 + tid;
  int v = (i < NN) ? cnt[i] : 0;
  int sc = v;
  for(int off=1; off<64; off<<=1){
    int t = __shfl_up(sc, off);
    if(lane >= off) sc += t;
  }
  if(lane==63) wsum[wv] = sc;
  __syncthreads();
  if(wv==0){
    int t = (lane<16) ? wsum[lane] : 0;
    for(int off=1; off<16; off<<=1){
      int u = __shfl_up(t, off);
      if(lane >= off) t += u;
    }
    if(lane<16) wsum[lane] = t;
  }
  __syncthreads();
  int woff = (wv==0) ? 0 : wsum[wv-1];
  int ex = s_boff + woff + sc - v;
  if(i < NN){ rowptr[i] = ex; cursor[i] = ex; }
  if(blockIdx.x==0 && tid==0) rowptr[NN] = NE;
}

/* blocks [0,NEB): CSR fill; blocks [NEB,...): hs = x*dso bf16 */
__global__ void k_fillhs(const int* __restrict__ ei, int* __restrict__ cursor,
                         int* __restrict__ eidx,
                         const float* __restrict__ x, const float* __restrict__ dso,
                         unsigned short* __restrict__ hs){
  if(blockIdx.x < NEB){
    int e = blockIdx.x*256 + threadIdx.x;
    if(e < NE){
      int c = ei[NE + e];
      int p = atomicAdd(&cursor[c], 1);
      eidx[p] = ei[e];
    }
  } else {
    int t = (blockIdx.x - NEB)*256 + threadIdx.x;   /* NN*64 */
    int row = t >> 6, c4 = (t & 63) << 2;
    if(row < NN){
      float s = dso[row];
      float4 v = *(const float4*)(x + (size_t)row*256 + c4);
      ushort4 o;
      o.x = f2bf(v.x*s); o.y = f2bf(v.y*s); o.z = f2bf(v.z*s); o.w = f2bf(v.w*s);
      *(ushort4*)(hs + (size_t)row*256 + c4) = o;
    }
  }
}

/* one node per HALF-WAVE, sequential node IDs (contiguous agg writes).
   Index broadcast + 8 independent 16B gathers in flight.
   NORM=1: contribution = relu(fma(v,cs,ch)) * dso[src], computed as
   fma(max(fma(v,cs,ch),0), dso, acc) - 4 VALU/elem. */
template<int NORM>
__global__ void k_agg(const unsigned short* __restrict__ src, const int* __restrict__ rowptr,
                      const int* __restrict__ eidx,
                      const float* __restrict__ cs, const float* __restrict__ ch,
                      const float* __restrict__ dso,
                      unsigned short* __restrict__ agg){
  int node = blockIdx.x*8 + (threadIdx.x >> 5);
  int l32 = threadIdx.x & 31;
  float csr[8], chr[8];
  if(NORM){
    #pragma unroll
    for(int k2=0;k2<8;k2++){ csr[k2] = cs[l32*8+k2]; chr[k2] = ch[l32*8+k2]; }
  }
  float a[8] = {0.f,0.f,0.f,0.f,0.f,0.f,0.f,0.f};
  int s = 0, e = 0;
  if(node < NN){ s = rowptr[node]; e = rowptr[node+1]; }
  int deg = e - s;
  for(int base=0; base<deg; base+=32){
    int cnt = min(deg - base, 32);
    int myidx = (base + l32 < deg) ? eidx[s + base + l32] : 0;
    for(int g=0; g<cnt; g+=8){
      int si[8];
      #pragma unroll
      for(int i=0;i<8;i++) si[i] = __shfl(myidx, g+i, 32);
      u16x8 v[8];
      #pragma unroll
      for(int i=0;i<8;i++) v[i] = *(const u16x8*)(src + (size_t)si[i]*256 + l32*8);
      float d[8];
      if(NORM){
        #pragma unroll
        for(int i=0;i<8;i++) d[i] = dso[si[i]];
      }
      #pragma unroll
      for(int i=0;i<8;i++){
        if(g+i < cnt){
          #pragma unroll
          for(int k2=0;k2<8;k2++){
            float y = bf2f(v[i][k2]);
            if(NORM) a[k2] = fmaf(fmaxf(fmaf(y, csr[k2], chr[k2]), 0.f), d[i], a[k2]);
            else     a[k2] += y;
          }
        }
      }
    }
  }
  if(node < MPAD){
    u16x8 o;
    #pragma unroll
    for(int k2=0;k2<8;k2++) o[k2] = f2bf(a[k2]);
    *(u16x8*)(agg + (size_t)node*256 + l32*8) = o;
  }
}

/* GEMM 64x128 tile, BK=64, double-buffered 48KB LDS, 2-phase:
   STAGE(next) issued BEFORE compute(cur); one __syncthreads per K-step.
   grid (2, 782). Epilogue operands hoisted before the K-loop.
   out[m][n] = (sum_k A[m][k]*W[k][n] + b[n]) * dsi[m] (+ residual).
   RESMODE: 0=none, 2=bf16 resb * per-row rds (layer0: hs*rds = x),
   3=bf16 resb + fused norm+relu (rcs/rch).
   STATS: per-(m-block,wm) column partials, transposed [col][NWID]. */
template<int RESMODE, int STATS, int OUTBF>
__global__ __launch_bounds__(256) void k_gemm(
    const unsigned short* __restrict__ A,    /* [MPAD][256] bf16 */
    const unsigned short* __restrict__ Bt,   /* [256][256] bf16 = W^T */
    const float* __restrict__ bias,
    const float* __restrict__ dsi,
    const unsigned short* __restrict__ resb,
    const float* __restrict__ rds,
    const float* __restrict__ rcs, const float* __restrict__ rch,
    void* __restrict__ outp,
    float* __restrict__ ps, float* __restrict__ pq)
{
  __shared__ __align__(16) unsigned char smem[49152];   /* 2 x (A 8KB + B 16KB) */
  const int tid = threadIdx.x;
  const int w = tid >> 6, lane = tid & 63;
  const int m0 = blockIdx.y * 64, n0 = blockIdx.x * 128;
  const int wm = w & 1, wn = w >> 1;

  /* ---- hoisted epilogue operands (fly under the K-loop) ---- */
  const int colb = n0 + wn*64 + (lane & 15);
  float bs[4], rcsv[4], rchv[4];
  #pragma unroll
  for(int nf=0; nf<4; ++nf) bs[nf] = bias[colb + nf*16];
  if(RESMODE==3){
    #pragma unroll
    for(int nf=0; nf<4; ++nf){ rcsv[nf] = rcs[colb + nf*16]; rchv[nf] = rch[colb + nf*16]; }
  }
  float dv[8], rdv[8];
  unsigned short rvb[32];
  #pragma unroll
  for(int mf=0; mf<2; ++mf){
    const int growb = m0 + wm*32 + mf*16 + ((lane>>4)<<2);
    #pragma unroll
    for(int j=0; j<4; ++j){
      const int grow = growb + j;
      const bool ok = grow < NN;
      dv[mf*4+j] = ok ? dsi[grow] : 0.f;
      if(RESMODE==2) rdv[mf*4+j] = ok ? rds[grow] : 0.f;
      if(RESMODE){
        const size_t rb = (size_t)grow * 256;
        #pragma unroll
        for(int nf=0; nf<4; ++nf)
          rvb[mf*16+j*4+nf] = ok ? resb[rb + colb + nf*16] : (unsigned short)0;
      }
    }
  }

  f32x4 acc[2][4];
  #pragma unroll
  for(int i=0;i<2;i++)
    #pragma unroll
    for(int j=0;j<4;j++) acc[i][j] = (f32x4){0.f,0.f,0.f,0.f};

  const char* Ab = (const char*)A;
  const char* Bb = (const char*)Bt;

  auto STAGE = [&](int buf, int kt){
    unsigned char* sA = smem + buf*24576;
    unsigned char* sB = sA + 8192;
    #pragma unroll
    for(int it=0; it<2; ++it){
      const int flat = it*256 + tid;
      const int row = flat >> 3, ch_ = flat & 7;
      const int sw = ch_ ^ (row & 7);
      gl_lds16(Ab + (size_t)(m0+row)*512 + kt*128 + sw*16,
               sA + (size_t)flat*16);
    }
    #pragma unroll
    for(int it=0; it<4; ++it){
      const int flat = it*256 + tid;
      const int row = flat >> 3, ch_ = flat & 7;
      const int sw = ch_ ^ (row & 7);
      gl_lds16(Bb + (size_t)(n0+row)*512 + kt*128 + sw*16,
               sB + (size_t)flat*16);
    }
  };

  STAGE(0, 0);
  __syncthreads();

  for(int kt=0; kt<4; ++kt){
    const int cur = kt & 1;
    if(kt < 3) STAGE(cur^1, kt+1);        /* loads fly during MFMA below */
    unsigned char* sA = smem + cur*24576;
    unsigned char* sB = sA + 8192;
    #pragma unroll
    for(int ks=0; ks<2; ++ks){
      const int ca = ks*4 + (lane >> 4);
      bf16x8 av[2], bv[4];
      #pragma unroll
      for(int f=0; f<2; ++f){
        const int ra = wm*32 + f*16 + (lane & 15);
        av[f] = *(const bf16x8*)(sA + ra*128 + ((ca ^ (ra & 7)) << 4));
      }
      #pragma unroll
      for(int f=0; f<4; ++f){
        const int rb = wn*64 + f*16 + (lane & 15);
        bv[f] = *(const bf16x8*)(sB + rb*128 + ((ca ^ (rb & 7)) << 4));
      }
      #pragma unroll
      for(int mf=0; mf<2; ++mf)
        #pragma unroll
        for(int nf=0; nf<4; ++nf)
          acc[mf][nf] = __builtin_amdgcn_mfma_f32_16x16x32_bf16(av[mf], bv[nf], acc[mf][nf], 0,0,0);
    }
    __syncthreads();   /* drains next-tile loads (overlapped with MFMA) */
  }

  /* ---- epilogue: C row = (lane>>4)*4+j, col = lane&15 (per 16x16 frag) ---- */
  float s[4] = {0.f,0.f,0.f,0.f}, q[4] = {0.f,0.f,0.f,0.f};
  #pragma unroll
  for(int mf=0; mf<2; ++mf){
    const int growb = m0 + wm*32 + mf*16 + ((lane>>4)<<2);
    #pragma unroll
    for(int j=0; j<4; ++j){
      const int grow = growb + j;
      if(grow < NN){
        const size_t rb = (size_t)grow * 256;
        #pragma unroll
        for(int nf=0; nf<4; ++nf){
          float v = (acc[mf][nf][j] + bs[nf]) * dv[mf*4+j];
          if(RESMODE==2) v += bf2f(rvb[mf*16+j*4+nf]) * rdv[mf*4+j];
          if(RESMODE==3) v += fmaxf(fmaf(bf2f(rvb[mf*16+j*4+nf]), rcsv[nf], rchv[nf]), 0.f);
          if(OUTBF) ((unsigned short*)outp)[rb + colb + nf*16] = f2bf(v);
          else      ((float*)outp)[rb + colb + nf*16] = v;
          if(STATS){ s[nf] += v; q[nf] += v*v; }
        }
      }
    }
  }
  if(STATS){
    const int wid = blockIdx.y*2 + wm;
    #pragma unroll
    for(int nf=0; nf<4; ++nf){
      float sv = s[nf], qv = q[nf];
      sv += __shfl_xor(sv, 16); sv += __shfl_xor(sv, 32);
      qv += __shfl_xor(qv, 16); qv += __shfl_xor(qv, 32);
      if(lane < 16){
        ps[(size_t)(colb + nf*16)*NWID + wid] = sv;
        pq[(size_t)(colb + nf*16)*NWID + wid] = qv;
      }
    }
  }
}

/* one block per column: reduce NWID partials (coalesced), finalize cs/ch */
__global__ void k_statsall(const float* __restrict__ ps, const float* __restrict__ pq,
                           const float* __restrict__ g, const float* __restrict__ be,
                           float* __restrict__ cs, float* __restrict__ ch){
  __shared__ float rs[4], rq[4];
  int c = blockIdx.x, t = threadIdx.x;
  float s = 0.f, q = 0.f;
  for(int r = t; r < NWID; r += 256){
    s += ps[(size_t)c*NWID + r];
    q += pq[(size_t)c*NWID + r];
  }
  for(int off=1; off<64; off<<=1){ s += __shfl_xor(s, off); q += __shfl_xor(q, off); }
  if((t & 63) == 0){ rs[t>>6] = s; rq[t>>6] = q; }
  __syncthreads();
  if(t == 0){
    float S = rs[0]+rs[1]+rs[2]+rs[3], Q = rq[0]+rq[1]+rq[2]+rq[3];
    float mu  = S * (1.0f/NN);
    float var = fmaxf(Q * (1.0f/NN) - mu*mu, 0.f);
    float inv = rsqrtf(var + EPSV);
    float sc = g[c] * inv;
    cs[c] = sc;
    ch[c] = be[c] - mu * sc;
  }
}

extern "C" void kernel_launch(void* const* d_in, const int* in_sizes, int n_in,
                              void* d_out, int out_size, void* d_ws, size_t ws_size,
                              hipStream_t stream){
  (void)in_sizes; (void)n_in; (void)out_size;
  const float* x  = (const float*)d_in[0];
  const int*   ei = (const int*)d_in[1];
  const float* Wl[3]  = {(const float*)d_in[2], (const float*)d_in[6], (const float*)d_in[10]};
  const float* bl[3]  = {(const float*)d_in[3], (const float*)d_in[7], (const float*)d_in[11]};
  const float* gl[2]  = {(const float*)d_in[4], (const float*)d_in[8]};
  const float* bel[2] = {(const float*)d_in[5], (const float*)d_in[9]};

  char* base = (char*)d_ws;
  size_t off = 0;
  auto alloc = [&](size_t bytes)->char* {
    char* r = base + off;
    off = (off + bytes + 511) & ~(size_t)511;
    return r;
  };
  int* degi_out = (int*)alloc((size_t)2*NN*4);
  int* degi_in  = degi_out + NN;
  float* dso    = (float*)alloc((size_t)NN*4);
  float* dsi    = (float*)alloc((size_t)NN*4);
  float* rds    = (float*)alloc((size_t)NN*4);
  int* rowptr   = (int*)alloc((size_t)(NN+1)*4);
  int* cursor   = (int*)alloc((size_t)NN*4);
  int* eidx     = (int*)alloc((size_t)NE*4);
  int* bsum     = (int*)alloc((size_t)NSB*4);
  unsigned short* Wt = (unsigned short*)alloc((size_t)3*65536*2);
  float* ps     = (float*)alloc((size_t)NWID*256*4);
  float* pq     = (float*)alloc((size_t)NWID*256*4);
  float* cs0    = (float*)alloc(1024);
  float* ch0    = (float*)alloc(1024);
  float* cs1    = (float*)alloc(1024);
  float* ch1    = (float*)alloc(1024);
  unsigned short* hs  = (unsigned short*)alloc((size_t)NN*256*2);
  unsigned short* agg = (unsigned short*)alloc((size_t)MPAD*256*2);
  unsigned short* ob0 = (unsigned short*)alloc((size_t)MPAD*256*2);
  unsigned short* ob1 = (unsigned short*)alloc((size_t)MPAD*256*2);
  if(off > ws_size) return;   /* workspace too small: fail visibly */

  /* graph prep (layer-invariant) */
  (void)hipMemsetAsync(degi_out, 0, (size_t)2*NN*4, stream);
  k_degreeW<<<NEB + 768, 256, 0, stream>>>(ei, degi_out, degi_in, Wl[0], Wl[1], Wl[2], Wt);
  k_bsum<<<NSB, 1024, 0, stream>>>(degi_in, degi_out, bsum, dso, dsi, rds);
  k_scatter<<<NSB, 1024, 0, stream>>>(degi_in, bsum, rowptr, cursor);
  k_fillhs<<<NEB + (NN*64+255)/256, 256, 0, stream>>>(ei, cursor, eidx, x, dso, hs);

  dim3 gg(2, 782);
  /* layer 0: gather hs; residual = hs * rds (= x), stats -> ob0 */
  k_agg<0><<<MPAD/8, 256, 0, stream>>>(hs, rowptr, eidx, nullptr, nullptr, nullptr, agg);
  k_gemm<2,1,1><<<gg, 256, 0, stream>>>(agg, Wt, bl[0], dsi, hs, rds, nullptr, nullptr,
                                        ob0, ps, pq);
  k_statsall<<<256, 256, 0, stream>>>(ps, pq, gl[0], bel[0], cs0, ch0);
  /* layer 1: gather = norm0(ob0) on the fly; residual = norm0(ob0) in epilogue */
  k_agg<1><<<MPAD/8, 256, 0, stream>>>(ob0, rowptr, eidx, cs0, ch0, dso, agg);
  k_gemm<3,1,1><<<gg, 256, 0, stream>>>(agg, Wt + 65536, bl[1], dsi, ob0, nullptr, cs0, ch0,
                                        ob1, ps, pq);
  k_statsall<<<256, 256, 0, stream>>>(ps, pq, gl[1], bel[1], cs1, ch1);
  /* layer 2: gather = norm1(ob1) on the fly; no residual, f32 out */
  k_agg<1><<<MPAD/8, 256, 0, stream>>>(ob1, rowptr, eidx, cs1, ch1, dso, agg);
  k_gemm<0,0,0><<<gg, 256, 0, stream>>>(agg, Wt + 2*65536, bl[2], dsi, nullptr, nullptr,
                                        nullptr, nullptr, d_out, nullptr, nullptr);
}